// Round 9
// baseline (116.894 us; speedup 1.0000x reference)
//
#include <hip/hip_runtime.h>
#include <hip/hip_bf16.h>

#define FP const float* __restrict__

typedef __attribute__((ext_vector_type(8))) short bf16x8;
typedef __attribute__((ext_vector_type(4))) float f32x4;

// ---------- helpers ----------
__device__ __forceinline__ void load8(const float* p, float* o) {
    const float4* v = reinterpret_cast<const float4*>(p);
    float4 a = v[0], b = v[1];
    o[0] = a.x; o[1] = a.y; o[2] = a.z; o[3] = a.w;
    o[4] = b.x; o[5] = b.y; o[6] = b.z; o[7] = b.w;
}

__device__ __forceinline__ float sigmoidf_(float x) {
    return 1.0f / (1.0f + __expf(-x));
}

__device__ __forceinline__ short f2bf(float x) {
    __hip_bfloat16 h = __float2bfloat16(x);
    return *reinterpret_cast<short*>(&h);
}

__device__ __forceinline__ bf16x8 load8_bf(const float* p) {
    float v[8];
    load8(p, v);
    bf16x8 r;
#pragma unroll
    for (int j = 0; j < 8; ++j) r[j] = f2bf(v[j]);
    return r;
}

// Fused kernel. Block regions:
//   [0,1024)    : out3 via MFMA, 8 16-row tiles per wave, XCD-swizzled (blk%8==b%8)
//   [1024,1536) : out2 (+fused _reduce(x3)), XCD-swizzled, shuffle-reduced
//   [1536,1552) : out0+out1 (one block per batch)
__global__ __launch_bounds__(256) void k_fused(
    FP x0, FP x1, FP x2, FP x3, FP W0, FP b0, FP W1, FP b1, FP W2, FP b2, FP W3, FP b3,
    float* __restrict__ out0, float* __restrict__ out1, float* __restrict__ out2,
    float* __restrict__ out3) {
    __shared__ float sm[3072];
    const int blk = blockIdx.x;
    const int tid = threadIdx.x;

    if (blk < 1024) {
        // ================= out3: MFMA 16x16x32 bf16 =================
        // Per 16-row tile: D[16 w][16 o] = F[16][96] @ W3[96][16] + b3
        // A-frag: lane holds F[m=lane&15][k=quad*8+j] == one load8 from x2/x3
        // B-frag: lane holds W3[k=quad*8+j][n=lane&15], preloaded once per wave
        // D: row = quad*4+reg, col = lane&15
        const int lane = tid & 63;
        const int wv = tid >> 6;   // wave in block
        const int q = lane >> 4;   // quad 0..3
        const int mn = lane & 15;  // m for A, n for B/D
        // swizzle: batch b pinned to XCD b%8
        const int xcd = blk & 7, inner = blk >> 3;    // inner 0..127
        const int b = xcd + 8 * (inner >> 6);         // 16 batches
        const int base = (inner & 63) * 32 + wv * 8;  // tile-in-batch, 8 tiles/wave
        const int u = base >> 6;                      // constant across the 8 tiles
        const unsigned bu = b * 32 + u, bbs = b * 32;

        // B fragments + bias: once per wave, reused for 8 tiles (24 MFMAs)
        bf16x8 Bf[3];
#pragma unroll
        for (int kb = 0; kb < 3; ++kb) {
#pragma unroll
            for (int j = 0; j < 8; ++j)
                Bf[kb][j] = f2bf(W3[(kb * 32 + q * 8 + j) * 16 + mn]);
        }
        const float bias = b3[mn];
        float* lds = sm + wv * 256;  // per-wave 16x16 staging tile (no barriers needed)

#pragma unroll 2
        for (int tt = 0; tt < 8; ++tt) {
            const int tb = base + tt;
            const int v = (tb >> 1) & 31;
            const int w0 = (tb & 1) * 16;
            const int w = w0 + mn;  // A-source row for this lane
            const unsigned bv = bbs + v;
            f32x4 acc = {bias, bias, bias, bias};

            // perm gather order (verified passing R5-R8):
            //  s0 x2[u,v]  s1 x3[u,v,w] | s2 x2[u,w]  s3 x3[u,w,v]
            //  s4 x2[v,u]  s5 x3[v,u,w] | s6 x2[w,u]  s7 x3[w,u,v]
            //  s8 x2[v,w]  s9 x3[v,w,u] | s10 x2[w,v] s11 x3[w,v,u]
            {
                // kb0: q0=s0 q1=s1 q2=s2 q3=s3
                unsigned e2 = (q == 0) ? (bu * 32 + v) : (bu * 32 + w);
                unsigned e3 = (q == 1) ? ((bu * 32 + v) * 32 + w) : ((bu * 32 + w) * 32 + v);
                const float* p = (q & 1) ? (x3 + (size_t)e3 * 8) : (x2 + (size_t)e2 * 8);
                bf16x8 a = load8_bf(p);
                acc = __builtin_amdgcn_mfma_f32_16x16x32_bf16(a, Bf[0], acc, 0, 0, 0);
            }
            {
                // kb1: q0=s4 q1=s5 q2=s6 q3=s7
                unsigned e2 = (q == 0) ? (bv * 32 + u) : ((bbs + w) * 32 + u);
                unsigned e3 = (q == 1) ? ((bv * 32 + u) * 32 + w) : (((bbs + w) * 32 + u) * 32 + v);
                const float* p = (q & 1) ? (x3 + (size_t)e3 * 8) : (x2 + (size_t)e2 * 8);
                bf16x8 a = load8_bf(p);
                acc = __builtin_amdgcn_mfma_f32_16x16x32_bf16(a, Bf[1], acc, 0, 0, 0);
            }
            {
                // kb2: q0=s8 q1=s9 q2=s10 q3=s11
                unsigned e2 = (q == 0) ? (bv * 32 + w) : ((bbs + w) * 32 + v);
                unsigned e3 = (q == 1) ? ((bv * 32 + w) * 32 + u) : (((bbs + w) * 32 + v) * 32 + u);
                const float* p = (q & 1) ? (x3 + (size_t)e3 * 8) : (x2 + (size_t)e2 * 8);
                bf16x8 a = load8_bf(p);
                acc = __builtin_amdgcn_mfma_f32_16x16x32_bf16(a, Bf[2], acc, 0, 0, 0);
            }

            // epilogue: sigmoid -> per-wave LDS tile -> lane-contiguous float4 store
#pragma unroll
            for (int rr = 0; rr < 4; ++rr)
                lds[(q * 4 + rr) * 16 + mn] = sigmoidf_(acc[rr]);
            float4 val = *reinterpret_cast<const float4*>(&lds[lane * 4]);
            const size_t rowbase = ((size_t)bu * 32 + v) * 32 + w0;
            *reinterpret_cast<float4*>(&out3[rowbase * 16 + lane * 4]) = val;
        }
    } else if (blk < 1536) {
        // ================= out2 (+reduce x3, vectorized + shuffle) =================
        float* Ws = sm;            // 1024
        float* bs = sm + 1024;     // 16
        float* sx1 = sm + 1040;    // 256
        float* sx2ij = sm + 1296;  // 256
        float* sx2ji = sm + 1552;  // 256
        float* rAmax = sm + 1808;  // 256
        float* rAmin = sm + 2064;  // 256
        float* rBmax = sm + 2320;  // 256
        float* rBmin = sm + 2576;  // 256
        int qq0 = blk - 1024;
        int xcd = qq0 & 7, inner = qq0 >> 3;
        int i = inner & 31;
        int b = xcd | ((inner >> 5) << 3);
        int bi = b * 32 + i;
        int jj = tid >> 3, sub = tid & 7;  // jj = j-row 0..31, sub = w-slice 0..7
        for (int t = tid; t < 1024; t += 256) Ws[t] = W2[t];
        if (tid < 16) bs[tid] = b2[tid];
        sx1[tid] = x1[(size_t)b * 256 + tid];
        sx2ij[tid] = x2[(size_t)bi * 256 + tid];
        sx2ji[tid] = x2[(((size_t)b * 32 + jj) * 32 + i) * 8 + sub];
        {
            // A: r3[b,i,jj,c] over w (diag w==jj); B: r3[b,jj,i,c] over w (diag w==i)
            // Each thread covers w = sub*4 .. sub*4+3 with contiguous load8s,
            // then butterfly-shuffles over the 8-lane sub group.
            float amax[8], amin[8], bmax[8], bmin[8];
#pragma unroll
            for (int c = 0; c < 8; ++c) {
                amax[c] = -1e30f; amin[c] = 1e30f;
                bmax[c] = -1e30f; bmin[c] = 1e30f;
            }
            const float* rowA = x3 + ((size_t)bi * 32 + jj) * 256;
            const float* rowB = x3 + (((size_t)b * 32 + jj) * 32 + i) * 256;
#pragma unroll
            for (int wi = 0; wi < 4; ++wi) {
                int w = sub * 4 + wi;
                float va[8], vb[8];
                load8(rowA + w * 8, va);
                load8(rowB + w * 8, vb);
                bool dA = (w == jj), dB = (w == i);
#pragma unroll
                for (int c = 0; c < 8; ++c) {
                    amax[c] = fmaxf(amax[c], dA ? 0.0f : va[c]);
                    amin[c] = fminf(amin[c], dA ? 1.0f : va[c]);
                    bmax[c] = fmaxf(bmax[c], dB ? 0.0f : vb[c]);
                    bmin[c] = fminf(bmin[c], dB ? 1.0f : vb[c]);
                }
            }
#pragma unroll
            for (int s = 1; s < 8; s <<= 1) {
#pragma unroll
                for (int c = 0; c < 8; ++c) {
                    amax[c] = fmaxf(amax[c], __shfl_xor(amax[c], s, 64));
                    amin[c] = fminf(amin[c], __shfl_xor(amin[c], s, 64));
                    bmax[c] = fmaxf(bmax[c], __shfl_xor(bmax[c], s, 64));
                    bmin[c] = fminf(bmin[c], __shfl_xor(bmin[c], s, 64));
                }
            }
            if (sub == 0) {
                *reinterpret_cast<float4*>(&rAmax[jj * 8]) = make_float4(amax[0], amax[1], amax[2], amax[3]);
                *reinterpret_cast<float4*>(&rAmax[jj * 8 + 4]) = make_float4(amax[4], amax[5], amax[6], amax[7]);
                *reinterpret_cast<float4*>(&rAmin[jj * 8]) = make_float4(amin[0], amin[1], amin[2], amin[3]);
                *reinterpret_cast<float4*>(&rAmin[jj * 8 + 4]) = make_float4(amin[4], amin[5], amin[6], amin[7]);
                *reinterpret_cast<float4*>(&rBmax[jj * 8]) = make_float4(bmax[0], bmax[1], bmax[2], bmax[3]);
                *reinterpret_cast<float4*>(&rBmax[jj * 8 + 4]) = make_float4(bmax[4], bmax[5], bmax[6], bmax[7]);
                *reinterpret_cast<float4*>(&rBmin[jj * 8]) = make_float4(bmin[0], bmin[1], bmin[2], bmin[3]);
                *reinterpret_cast<float4*>(&rBmin[jj * 8 + 4]) = make_float4(bmin[4], bmin[5], bmin[6], bmin[7]);
            }
        }
        __syncthreads();
#pragma unroll
        for (int qq = 0; qq < 2; ++qq) {
            int idx = tid + qq * 256;
            int j2 = idx >> 4, o = idx & 15;
            float acc = bs[o];
#pragma unroll
            for (int cc = 0; cc < 8; ++cc) {
                int jc = j2 * 8 + cc;
                acc += sx1[i * 8 + cc] * Ws[(0 + cc) * 16 + o];
                acc += sx2ij[jc] * Ws[(8 + cc) * 16 + o];
                acc += rAmax[jc] * Ws[(16 + cc) * 16 + o];
                acc += rAmin[jc] * Ws[(24 + cc) * 16 + o];
                acc += sx1[jc] * Ws[(32 + cc) * 16 + o];
                acc += sx2ji[jc] * Ws[(40 + cc) * 16 + o];
                acc += rBmax[jc] * Ws[(48 + cc) * 16 + o];
                acc += rBmin[jc] * Ws[(56 + cc) * 16 + o];
            }
            out2[((size_t)bi * 32 + j2) * 16 + o] = sigmoidf_(acc);
        }
    } else {
        // ================= out0 + out1 =================
        float* s2max = sm;        // 256
        float* s2min = sm + 256;  // 256
        float* sx1 = sm + 512;    // 256
        float* sx0 = sm + 768;    // 8
        float* m1max = sm + 776;  // 8
        float* m1min = sm + 784;  // 8
        int b = blk - 1536;
        int i = tid >> 3, c = tid & 7;
        {
            const float* p = x2 + ((size_t)(b * 32 + i) * 32) * 8 + c;
            float vmax = -1e30f, vmin = 1e30f;
            for (int j2 = 0; j2 < 32; ++j2) {
                float v = p[j2 * 8];
                vmax = fmaxf(vmax, (j2 == i) ? 0.0f : v);
                vmin = fminf(vmin, (j2 == i) ? 1.0f : v);
            }
            s2max[tid] = vmax;
            s2min[tid] = vmin;
        }
        sx1[tid] = x1[(size_t)b * 256 + tid];
        if (tid < 8) sx0[tid] = x0[b * 8 + tid];
        __syncthreads();
        if (tid < 8) {
            float mx = -1e30f, mn = 1e30f;
            for (int ii = 0; ii < 32; ++ii) {
                float v = sx1[ii * 8 + tid];
                mx = fmaxf(mx, v);
                mn = fminf(mn, v);
            }
            m1max[tid] = mx;
            m1min[tid] = mn;
        }
        __syncthreads();
#pragma unroll
        for (int qq = 0; qq < 2; ++qq) {
            int idx = tid + qq * 256;
            int i2 = idx >> 4, o = idx & 15;
            float acc = b1[o];
#pragma unroll
            for (int cc = 0; cc < 8; ++cc) {
                acc += sx0[cc] * W1[cc * 16 + o];
                acc += sx1[i2 * 8 + cc] * W1[(8 + cc) * 16 + o];
                acc += s2max[i2 * 8 + cc] * W1[(16 + cc) * 16 + o];
                acc += s2min[i2 * 8 + cc] * W1[(24 + cc) * 16 + o];
            }
            out1[((size_t)b * 32 + i2) * 16 + o] = sigmoidf_(acc);
        }
        if (tid < 16) {
            int o = tid;
            float acc = b0[o];
#pragma unroll
            for (int cc = 0; cc < 8; ++cc) {
                acc += sx0[cc] * W0[cc * 16 + o];
                acc += m1max[cc] * W0[(8 + cc) * 16 + o];
                acc += m1min[cc] * W0[(16 + cc) * 16 + o];
            }
            out0[b * 16 + o] = sigmoidf_(acc);
        }
    }
}

extern "C" void kernel_launch(void* const* d_in, const int* in_sizes, int n_in, void* d_out,
                              int out_size, void* d_ws, size_t ws_size, hipStream_t stream) {
    // Identify inputs by their UNIQUE flat element counts (robust to ordering).
    const float *x0 = nullptr, *x1 = nullptr, *x2 = nullptr, *x3 = nullptr;
    const float *W0 = nullptr, *W1 = nullptr, *W2 = nullptr, *W3 = nullptr;
    const float* bb[4] = {nullptr, nullptr, nullptr, nullptr};
    int nb = 0;
    for (int k = 0; k < n_in; ++k) {
        const float* p = (const float*)d_in[k];
        switch (in_sizes[k]) {
            case 128:     x0 = p; break;
            case 4096:    x1 = p; break;
            case 131072:  x2 = p; break;
            case 4194304: x3 = p; break;
            case 384:     W0 = p; break;
            case 512:     W1 = p; break;
            case 1024:    W2 = p; break;
            case 1536:    W3 = p; break;
            case 16:      if (nb < 4) bb[nb++] = p; break;
            default: break;
        }
    }
    if (!x0) x0 = (const float*)d_in[0];
    if (!x1) x1 = (const float*)d_in[1];
    if (!x2) x2 = (const float*)d_in[2];
    if (!x3) x3 = (const float*)d_in[3];
    if (!W0) W0 = (const float*)d_in[4];
    if (!W1) W1 = (const float*)d_in[6];
    if (!W2) W2 = (const float*)d_in[8];
    if (!W3) W3 = (const float*)d_in[10];
    const float* b0 = nb > 0 ? bb[0] : (const float*)d_in[5];
    const float* b1 = nb > 1 ? bb[1] : (const float*)d_in[7];
    const float* b2 = nb > 2 ? bb[2] : (const float*)d_in[9];
    const float* b3 = nb > 3 ? bb[3] : (const float*)d_in[11];

    // Output is FP32 (reference output dtype), concatenated flat in return order.
    float* out = (float*)d_out;
    float* out0 = out;           // [16,16]          = 256
    float* out1 = out + 256;     // [16,32,16]       = 8192
    float* out2 = out + 8448;    // [16,32,32,16]    = 262144
    float* out3 = out + 270592;  // [16,32,32,32,16] = 8388608

    k_fused<<<1552, 256, 0, stream>>>(x0, x1, x2, x3, W0, b0, W1, b1, W2, b2, W3, b3,
                                      out0, out1, out2, out3);
}

// Round 10
// 112.997 us; speedup vs baseline: 1.0345x; 1.0345x over previous
//
#include <hip/hip_runtime.h>
#include <hip/hip_bf16.h>

#define FP const float* __restrict__

typedef __attribute__((ext_vector_type(8))) short bf16x8;
typedef __attribute__((ext_vector_type(4))) float f32x4;

// ---------- helpers ----------
__device__ __forceinline__ void load8(const float* p, float* o) {
    const float4* v = reinterpret_cast<const float4*>(p);
    float4 a = v[0], b = v[1];
    o[0] = a.x; o[1] = a.y; o[2] = a.z; o[3] = a.w;
    o[4] = b.x; o[5] = b.y; o[6] = b.z; o[7] = b.w;
}

__device__ __forceinline__ float sigmoidf_(float x) {
    return 1.0f / (1.0f + __expf(-x));
}

__device__ __forceinline__ short f2bf(float x) {
    __hip_bfloat16 h = __float2bfloat16(x);
    return *reinterpret_cast<short*>(&h);
}

__device__ __forceinline__ bf16x8 load8_bf(const float* p) {
    float v[8];
    load8(p, v);
    bf16x8 r;
#pragma unroll
    for (int j = 0; j < 8; ++j) r[j] = f2bf(v[j]);
    return r;
}

// Fused kernel. Block regions:
//   [0,1024)    : out3 via MFMA, 8 16-row tiles per wave, XCD-swizzled (blk%8==b%8)
//   [1024,1536) : out2 (+fused _reduce(x3)), XCD-swizzled
//   [1536,1552) : out0+out1 (one block per batch)
__global__ __launch_bounds__(256) void k_fused(
    FP x0, FP x1, FP x2, FP x3, FP W0, FP b0, FP W1, FP b1, FP W2, FP b2, FP W3, FP b3,
    float* __restrict__ out0, float* __restrict__ out1, float* __restrict__ out2,
    float* __restrict__ out3) {
    __shared__ float sm[3072];
    const int blk = blockIdx.x;
    const int tid = threadIdx.x;

    if (blk < 1024) {
        // ================= out3: MFMA 16x16x32 bf16 =================
        // Per 16-row tile: D[16 w][16 o] = F[16][96] @ W3[96][16] + b3
        // A-frag: lane holds F[m=lane&15][k=quad*8+j] == one load8 from x2/x3
        // B-frag: lane holds W3[k=quad*8+j][n=lane&15], preloaded once per wave
        // D: row = quad*4+reg, col = lane&15
        const int lane = tid & 63;
        const int wv = tid >> 6;   // wave in block
        const int q = lane >> 4;   // quad 0..3
        const int mn = lane & 15;  // m for A, n for B/D
        // swizzle: batch b pinned to XCD b%8
        const int xcd = blk & 7, inner = blk >> 3;    // inner 0..127
        const int b = xcd + 8 * (inner >> 6);         // 16 batches
        const int base = (inner & 63) * 32 + wv * 8;  // tile-in-batch, 8 tiles/wave
        const int u = base >> 6;                      // constant across the 8 tiles
        const unsigned bu = b * 32 + u, bbs = b * 32;

        // B fragments + bias: once per wave, reused for 8 tiles (24 MFMAs)
        bf16x8 Bf[3];
#pragma unroll
        for (int kb = 0; kb < 3; ++kb) {
#pragma unroll
            for (int j = 0; j < 8; ++j)
                Bf[kb][j] = f2bf(W3[(kb * 32 + q * 8 + j) * 16 + mn]);
        }
        const float bias = b3[mn];
        float* lds = sm + wv * 256;  // per-wave 16x16 staging tile (no barriers needed)

#pragma unroll 2
        for (int tt = 0; tt < 8; ++tt) {
            const int tb = base + tt;
            const int v = (tb >> 1) & 31;
            const int w0 = (tb & 1) * 16;
            const int w = w0 + mn;  // A-source row for this lane
            const unsigned bv = bbs + v;
            f32x4 acc = {bias, bias, bias, bias};

            // perm gather order (verified passing R5-R9):
            //  s0 x2[u,v]  s1 x3[u,v,w] | s2 x2[u,w]  s3 x3[u,w,v]
            //  s4 x2[v,u]  s5 x3[v,u,w] | s6 x2[w,u]  s7 x3[w,u,v]
            //  s8 x2[v,w]  s9 x3[v,w,u] | s10 x2[w,v] s11 x3[w,v,u]
            {
                // kb0: q0=s0 q1=s1 q2=s2 q3=s3
                unsigned e2 = (q == 0) ? (bu * 32 + v) : (bu * 32 + w);
                unsigned e3 = (q == 1) ? ((bu * 32 + v) * 32 + w) : ((bu * 32 + w) * 32 + v);
                const float* p = (q & 1) ? (x3 + (size_t)e3 * 8) : (x2 + (size_t)e2 * 8);
                bf16x8 a = load8_bf(p);
                acc = __builtin_amdgcn_mfma_f32_16x16x32_bf16(a, Bf[0], acc, 0, 0, 0);
            }
            {
                // kb1: q0=s4 q1=s5 q2=s6 q3=s7
                unsigned e2 = (q == 0) ? (bv * 32 + u) : ((bbs + w) * 32 + u);
                unsigned e3 = (q == 1) ? ((bv * 32 + u) * 32 + w) : (((bbs + w) * 32 + u) * 32 + v);
                const float* p = (q & 1) ? (x3 + (size_t)e3 * 8) : (x2 + (size_t)e2 * 8);
                bf16x8 a = load8_bf(p);
                acc = __builtin_amdgcn_mfma_f32_16x16x32_bf16(a, Bf[1], acc, 0, 0, 0);
            }
            {
                // kb2: q0=s8 q1=s9 q2=s10 q3=s11
                unsigned e2 = (q == 0) ? (bv * 32 + w) : ((bbs + w) * 32 + v);
                unsigned e3 = (q == 1) ? ((bv * 32 + w) * 32 + u) : (((bbs + w) * 32 + v) * 32 + u);
                const float* p = (q & 1) ? (x3 + (size_t)e3 * 8) : (x2 + (size_t)e2 * 8);
                bf16x8 a = load8_bf(p);
                acc = __builtin_amdgcn_mfma_f32_16x16x32_bf16(a, Bf[2], acc, 0, 0, 0);
            }

            // epilogue: sigmoid -> per-wave LDS tile -> lane-contiguous float4 store
#pragma unroll
            for (int rr = 0; rr < 4; ++rr)
                lds[(q * 4 + rr) * 16 + mn] = sigmoidf_(acc[rr]);
            float4 val = *reinterpret_cast<const float4*>(&lds[lane * 4]);
            const size_t rowbase = ((size_t)bu * 32 + v) * 32 + w0;
            *reinterpret_cast<float4*>(&out3[rowbase * 16 + lane * 4]) = val;
        }
    } else if (blk < 1536) {
        // ================= out2 (+reduce x3) =================
        float* Ws = sm;            // 1024
        float* bs = sm + 1024;     // 16
        float* sx1 = sm + 1040;    // 256
        float* sx2ij = sm + 1296;  // 256
        float* sx2ji = sm + 1552;  // 256
        float* rAmax = sm + 1808;  // 256
        float* rAmin = sm + 2064;  // 256
        float* rBmax = sm + 2320;  // 256
        float* rBmin = sm + 2576;  // 256
        int qq0 = blk - 1024;
        int xcd = qq0 & 7, inner = qq0 >> 3;
        int i = inner & 31;
        int b = xcd | ((inner >> 5) << 3);
        int bi = b * 32 + i;
        int j = tid >> 3, c = tid & 7;
        for (int t = tid; t < 1024; t += 256) Ws[t] = W2[t];
        if (tid < 16) bs[tid] = b2[tid];
        sx1[tid] = x1[(size_t)b * 256 + tid];
        sx2ij[tid] = x2[(size_t)bi * 256 + tid];
        sx2ji[tid] = x2[(((size_t)b * 32 + j) * 32 + i) * 8 + c];
        {
            // A: r3[b,i,j,c] over w (diag w==j); B: r3[b,j,i,c] over w (diag w==i)
            const float* pA = x3 + ((size_t)bi * 32 + j) * 256 + c;
            const float* pB = x3 + (((size_t)b * 32 + j) * 32 + i) * 256 + c;
            float amax = -1e30f, amin = 1e30f, bmax = -1e30f, bmin = 1e30f;
            for (int w = 0; w < 32; ++w) {
                float va = pA[w * 8], vb = pB[w * 8];
                bool dA = (w == j), dB = (w == i);
                amax = fmaxf(amax, dA ? 0.0f : va);
                amin = fminf(amin, dA ? 1.0f : va);
                bmax = fmaxf(bmax, dB ? 0.0f : vb);
                bmin = fminf(bmin, dB ? 1.0f : vb);
            }
            rAmax[tid] = amax; rAmin[tid] = amin;
            rBmax[tid] = bmax; rBmin[tid] = bmin;
        }
        __syncthreads();
#pragma unroll
        for (int qq = 0; qq < 2; ++qq) {
            int idx = tid + qq * 256;
            int j2 = idx >> 4, o = idx & 15;
            float acc = bs[o];
#pragma unroll
            for (int cc = 0; cc < 8; ++cc) {
                int jc = j2 * 8 + cc;
                acc += sx1[i * 8 + cc] * Ws[(0 + cc) * 16 + o];
                acc += sx2ij[jc] * Ws[(8 + cc) * 16 + o];
                acc += rAmax[jc] * Ws[(16 + cc) * 16 + o];
                acc += rAmin[jc] * Ws[(24 + cc) * 16 + o];
                acc += sx1[jc] * Ws[(32 + cc) * 16 + o];
                acc += sx2ji[jc] * Ws[(40 + cc) * 16 + o];
                acc += rBmax[jc] * Ws[(48 + cc) * 16 + o];
                acc += rBmin[jc] * Ws[(56 + cc) * 16 + o];
            }
            out2[((size_t)bi * 32 + j2) * 16 + o] = sigmoidf_(acc);
        }
    } else {
        // ================= out0 + out1 =================
        float* s2max = sm;        // 256
        float* s2min = sm + 256;  // 256
        float* sx1 = sm + 512;    // 256
        float* sx0 = sm + 768;    // 8
        float* m1max = sm + 776;  // 8
        float* m1min = sm + 784;  // 8
        int b = blk - 1536;
        int i = tid >> 3, c = tid & 7;
        {
            const float* p = x2 + ((size_t)(b * 32 + i) * 32) * 8 + c;
            float vmax = -1e30f, vmin = 1e30f;
            for (int j2 = 0; j2 < 32; ++j2) {
                float v = p[j2 * 8];
                vmax = fmaxf(vmax, (j2 == i) ? 0.0f : v);
                vmin = fminf(vmin, (j2 == i) ? 1.0f : v);
            }
            s2max[tid] = vmax;
            s2min[tid] = vmin;
        }
        sx1[tid] = x1[(size_t)b * 256 + tid];
        if (tid < 8) sx0[tid] = x0[b * 8 + tid];
        __syncthreads();
        if (tid < 8) {
            float mx = -1e30f, mn = 1e30f;
            for (int ii = 0; ii < 32; ++ii) {
                float v = sx1[ii * 8 + tid];
                mx = fmaxf(mx, v);
                mn = fminf(mn, v);
            }
            m1max[tid] = mx;
            m1min[tid] = mn;
        }
        __syncthreads();
#pragma unroll
        for (int qq = 0; qq < 2; ++qq) {
            int idx = tid + qq * 256;
            int i2 = idx >> 4, o = idx & 15;
            float acc = b1[o];
#pragma unroll
            for (int cc = 0; cc < 8; ++cc) {
                acc += sx0[cc] * W1[cc * 16 + o];
                acc += sx1[i2 * 8 + cc] * W1[(8 + cc) * 16 + o];
                acc += s2max[i2 * 8 + cc] * W1[(16 + cc) * 16 + o];
                acc += s2min[i2 * 8 + cc] * W1[(24 + cc) * 16 + o];
            }
            out1[((size_t)b * 32 + i2) * 16 + o] = sigmoidf_(acc);
        }
        if (tid < 16) {
            int o = tid;
            float acc = b0[o];
#pragma unroll
            for (int cc = 0; cc < 8; ++cc) {
                acc += sx0[cc] * W0[cc * 16 + o];
                acc += m1max[cc] * W0[(8 + cc) * 16 + o];
                acc += m1min[cc] * W0[(16 + cc) * 16 + o];
            }
            out0[b * 16 + o] = sigmoidf_(acc);
        }
    }
}

extern "C" void kernel_launch(void* const* d_in, const int* in_sizes, int n_in, void* d_out,
                              int out_size, void* d_ws, size_t ws_size, hipStream_t stream) {
    // Identify inputs by their UNIQUE flat element counts (robust to ordering).
    const float *x0 = nullptr, *x1 = nullptr, *x2 = nullptr, *x3 = nullptr;
    const float *W0 = nullptr, *W1 = nullptr, *W2 = nullptr, *W3 = nullptr;
    const float* bb[4] = {nullptr, nullptr, nullptr, nullptr};
    int nb = 0;
    for (int k = 0; k < n_in; ++k) {
        const float* p = (const float*)d_in[k];
        switch (in_sizes[k]) {
            case 128:     x0 = p; break;
            case 4096:    x1 = p; break;
            case 131072:  x2 = p; break;
            case 4194304: x3 = p; break;
            case 384:     W0 = p; break;
            case 512:     W1 = p; break;
            case 1024:    W2 = p; break;
            case 1536:    W3 = p; break;
            case 16:      if (nb < 4) bb[nb++] = p; break;
            default: break;
        }
    }
    if (!x0) x0 = (const float*)d_in[0];
    if (!x1) x1 = (const float*)d_in[1];
    if (!x2) x2 = (const float*)d_in[2];
    if (!x3) x3 = (const float*)d_in[3];
    if (!W0) W0 = (const float*)d_in[4];
    if (!W1) W1 = (const float*)d_in[6];
    if (!W2) W2 = (const float*)d_in[8];
    if (!W3) W3 = (const float*)d_in[10];
    const float* b0 = nb > 0 ? bb[0] : (const float*)d_in[5];
    const float* b1 = nb > 1 ? bb[1] : (const float*)d_in[7];
    const float* b2 = nb > 2 ? bb[2] : (const float*)d_in[9];
    const float* b3 = nb > 3 ? bb[3] : (const float*)d_in[11];

    // Output is FP32 (reference output dtype), concatenated flat in return order.
    float* out = (float*)d_out;
    float* out0 = out;           // [16,16]          = 256
    float* out1 = out + 256;     // [16,32,16]       = 8192
    float* out2 = out + 8448;    // [16,32,32,16]    = 262144
    float* out3 = out + 270592;  // [16,32,32,32,16] = 8388608

    k_fused<<<1552, 256, 0, stream>>>(x0, x1, x2, x3, W0, b0, W1, b1, W2, b2, W3, b3,
                                      out0, out1, out2, out3);
}